// Round 4
// baseline (286.250 us; speedup 1.0000x reference)
//
#include <hip/hip_runtime.h>
#include <stdint.h>

#define NNODES 100000
#define NEDGES 1600000
#define NBIN 391        // ceil(NNODES/256), bin = node >> 8
#define EPB 4096        // edges per block in build passes
#define NB 391          // ceil(NEDGES/EPB)

typedef unsigned short bf16_t;
typedef __attribute__((ext_vector_type(8))) short bf16x8;   // MFMA A/B frag (8 bf16)
typedef __attribute__((ext_vector_type(8))) unsigned short u16x8;
typedef __attribute__((ext_vector_type(4))) float f32x4;    // MFMA C/D frag

__device__ __forceinline__ float bf2f(unsigned short u) {
  return __uint_as_float(((unsigned)u) << 16);
}
__device__ __forceinline__ unsigned short f2bf(float f) {
  unsigned u = __float_as_uint(f);
  return (unsigned short)((u + 0x7FFFu + ((u >> 16) & 1u)) >> 16);  // RNE
}
__device__ __forceinline__ void gload_lds16(const void* g, void* lds) {
  __builtin_amdgcn_global_load_lds(
      (const __attribute__((address_space(1))) unsigned int*)g,
      (__attribute__((address_space(3))) unsigned int*)lds, 16, 0, 0);
}

// ---------------- pass 1: per-block LDS histograms over dst-bins and src-bins ----------------
__global__ __launch_bounds__(256) void hist2_kernel(
    const int* __restrict__ src, const int* __restrict__ dst,
    int* __restrict__ cntD, int* __restrict__ cntS) {
  __shared__ int hD[NBIN], hS[NBIN];
  int blk = blockIdx.x, t = threadIdx.x;
  for (int i = t; i < NBIN; i += 256) { hD[i] = 0; hS[i] = 0; }
  __syncthreads();
  int e0 = blk * EPB + t * 16;
  if (e0 + 15 < NEDGES) {
#pragma unroll
    for (int q = 0; q < 4; q++) {
      int4 s4 = *reinterpret_cast<const int4*>(src + e0 + q * 4);
      int4 d4 = *reinterpret_cast<const int4*>(dst + e0 + q * 4);
      atomicAdd(&hD[d4.x >> 8], 1); atomicAdd(&hS[s4.x >> 8], 1);
      atomicAdd(&hD[d4.y >> 8], 1); atomicAdd(&hS[s4.y >> 8], 1);
      atomicAdd(&hD[d4.z >> 8], 1); atomicAdd(&hS[s4.z >> 8], 1);
      atomicAdd(&hD[d4.w >> 8], 1); atomicAdd(&hS[s4.w >> 8], 1);
    }
  } else {
    for (int e = e0; e < NEDGES && e < e0 + 16; e++) {
      atomicAdd(&hD[dst[e] >> 8], 1);
      atomicAdd(&hS[src[e] >> 8], 1);
    }
  }
  __syncthreads();
  for (int i = t; i < NBIN; i += 256) {
    cntD[(size_t)blk * NBIN + i] = hD[i];
    cntS[(size_t)blk * NBIN + i] = hS[i];
  }
}

// ---------------- pass 2a: per-bin exclusive scan across blocks (in place) ----------------
__global__ __launch_bounds__(512) void scan_bin_kernel(
    int* __restrict__ cntD, int* __restrict__ cntS, int* __restrict__ binTot) {
  __shared__ int lds[512];
  int g = blockIdx.x, t = threadIdx.x;
  int* cnt = (g < NBIN) ? cntD : cntS;
  int gg = (g < NBIN) ? g : g - NBIN;
  int v = (t < NB) ? cnt[(size_t)t * NBIN + gg] : 0;
  lds[t] = v;
  __syncthreads();
  for (int off = 1; off < 512; off <<= 1) {
    int a = (t >= off) ? lds[t - off] : 0;
    __syncthreads();
    lds[t] += a;
    __syncthreads();
  }
  if (t < NB) cnt[(size_t)t * NBIN + gg] = lds[t] - v;  // exclusive
  if (t == 0) binTot[g] = lds[511];
}

// ---------------- pass 2b (block 0): bin bases; blocks 1..: weight cast+transpose ----------------
__global__ __launch_bounds__(512) void base_wcast_kernel(
    const int* __restrict__ binTot, int* __restrict__ binbaseD,
    int* __restrict__ binbaseS, int* __restrict__ row_ptr,
    const float* __restrict__ W1, const float* __restrict__ W2,
    bf16_t* __restrict__ W1t, bf16_t* __restrict__ W2t) {
  if (blockIdx.x == 0) {
    __shared__ int lds[512];
    int t = threadIdx.x;
    int v = (t < NBIN) ? binTot[t] : 0;
    lds[t] = v;
    __syncthreads();
    for (int off = 1; off < 512; off <<= 1) {
      int a = (t >= off) ? lds[t - off] : 0;
      __syncthreads();
      lds[t] += a;
      __syncthreads();
    }
    if (t < NBIN) binbaseD[t] = lds[t] - v;
    if (t == NBIN - 1) { binbaseD[NBIN] = lds[t]; row_ptr[NNODES] = lds[t]; }
    __syncthreads();
    int v2 = (t < NBIN) ? binTot[NBIN + t] : 0;
    lds[t] = v2;
    __syncthreads();
    for (int off = 1; off < 512; off <<= 1) {
      int a = (t >= off) ? lds[t - off] : 0;
      __syncthreads();
      lds[t] += a;
      __syncthreads();
    }
    if (t < NBIN) binbaseS[t] = lds[t] - v2;
    if (t == NBIN - 1) binbaseS[NBIN] = lds[t];
  } else {
    int i = (blockIdx.x - 1) * 512 + threadIdx.x;  // 0..65535
    if (i < 32768) {
      int n = i / 128, k = i % 128;                 // W1t[n][k] = W1[k][n]
      W1t[i] = f2bf(W1[(size_t)k * 256 + n]);
    } else if (i < 65536) {
      int j = i - 32768;
      int n = j / 256, k = j % 256;                 // W2t[n][k] = W2[k][n]
      W2t[j] = f2bf(W2[(size_t)k * 128 + n]);
    }
  }
}

// ---------------- pass 3: scatter records to bins (LDS cursors, no global atomics) ----------------
__global__ __launch_bounds__(256) void scatter_recs_kernel(
    const int* __restrict__ src, const int* __restrict__ dst,
    const int* __restrict__ cntD, const int* __restrict__ cntS,
    const int* __restrict__ binbaseD, const int* __restrict__ binbaseS,
    unsigned int* __restrict__ recD, unsigned char* __restrict__ recS) {
  __shared__ int cD[NBIN], cS[NBIN];
  int blk = blockIdx.x, t = threadIdx.x;
  for (int i = t; i < NBIN; i += 256) {
    cD[i] = binbaseD[i] + cntD[(size_t)blk * NBIN + i];
    cS[i] = binbaseS[i] + cntS[(size_t)blk * NBIN + i];
  }
  __syncthreads();
  int e0 = blk * EPB + t * 16;
  if (e0 + 15 < NEDGES) {
#pragma unroll
    for (int q = 0; q < 4; q++) {
      int4 s4 = *reinterpret_cast<const int4*>(src + e0 + q * 4);
      int4 d4 = *reinterpret_cast<const int4*>(dst + e0 + q * 4);
      int ss[4] = {s4.x, s4.y, s4.z, s4.w};
      int dd[4] = {d4.x, d4.y, d4.z, d4.w};
#pragma unroll
      for (int i = 0; i < 4; i++) {
        int s = ss[i], d = dd[i];
        int pos = atomicAdd(&cD[d >> 8], 1);
        recD[pos] = ((unsigned)s << 8) | (unsigned)(d & 255);
        int ps = atomicAdd(&cS[s >> 8], 1);
        recS[ps] = (unsigned char)(s & 255);
      }
    }
  } else {
    for (int e = e0; e < NEDGES && e < e0 + 16; e++) {
      int s = src[e], d = dst[e];
      int pos = atomicAdd(&cD[d >> 8], 1);
      recD[pos] = ((unsigned)s << 8) | (unsigned)(d & 255);
      int ps = atomicAdd(&cS[s >> 8], 1);
      recS[ps] = (unsigned char)(s & 255);
    }
  }
}

// ---------------- fused finish ----------------
__global__ __launch_bounds__(512) void finish2_kernel(
    const unsigned int* __restrict__ recD, const int* __restrict__ binbaseD,
    const unsigned char* __restrict__ recS, const int* __restrict__ binbaseS,
    int* __restrict__ row_ptr, float* __restrict__ in_norm, int* __restrict__ csr,
    float* __restrict__ out_norm, const float* __restrict__ x, bf16_t* __restrict__ xb) {
  __shared__ int hist[4096];
  __shared__ int cur[4096];
  __shared__ int sc[512];
  __shared__ float onv[256];
  int t = threadIdx.x;
  if (blockIdx.x < NBIN) {
    int b = blockIdx.x;
    int base = binbaseD[b];
    int cnt = binbaseD[b + 1] - base;
    for (int i = t; i < 4096; i += 512) hist[i] = 0;
    __syncthreads();
    const unsigned int* rec = recD + base;
    for (int i = t; i < cnt; i += 512) {
      unsigned int r = rec[i];
      atomicAdd(&hist[((r & 255u) << 4) | (r >> 21)], 1);  // src>>13 = r>>21 (0..12)
    }
    __syncthreads();
    int loc[8];
    int lsum = 0;
#pragma unroll
    for (int i = 0; i < 8; i++) { loc[i] = lsum; lsum += hist[t * 8 + i]; }
    sc[t] = lsum;
    __syncthreads();
    for (int off = 1; off < 512; off <<= 1) {
      int a = (t >= off) ? sc[t - off] : 0;
      __syncthreads();
      sc[t] += a;
      __syncthreads();
    }
    int toff = sc[t] - lsum;  // exclusive across threads
#pragma unroll
    for (int i = 0; i < 8; i++) cur[t * 8 + i] = base + toff + loc[i];
    __syncthreads();
    if (t < 256) {
      int n = (b << 8) + t;
      if (n < NNODES) {
        row_ptr[n] = cur[t * 16];
        int v = 0;
#pragma unroll
        for (int p = 0; p < 16; p++) v += hist[t * 16 + p];
        in_norm[n] = rsqrtf((float)(v > 0 ? v : 1));
      }
    }
    __syncthreads();
    for (int i = t; i < cnt; i += 512) {
      unsigned int r = rec[i];
      int key = ((r & 255u) << 4) | (r >> 21);
      int slot = atomicAdd(&cur[key], 1);
      csr[slot] = (int)(r >> 8);
    }
  } else {
    int b = blockIdx.x - NBIN;
    int base = binbaseS[b];
    int cnt = binbaseS[b + 1] - base;
    if (t < 256) hist[t] = 0;
    __syncthreads();
    const unsigned char* rec = recS + base;
    for (int i = t; i < cnt; i += 512) atomicAdd(&hist[rec[i]], 1);
    __syncthreads();
    int n0 = b << 8;
    if (t < 256) {
      int v = hist[t];
      float on = rsqrtf((float)(v > 0 ? v : 1));
      onv[t] = on;
      int n = n0 + t;
      if (n < NNODES) out_norm[n] = on;
    }
    __syncthreads();
    for (int idx = t; idx < 256 * 16; idx += 512) {
      int r16 = idx >> 4, chunk = idx & 15;
      int n = n0 + r16;
      if (n >= NNODES) break;
      float s = onv[r16];
      const float4* xp = reinterpret_cast<const float4*>(x + (size_t)n * 128 + chunk * 8);
      float4 v0 = xp[0], v1 = xp[1];
      u16x8 u;
      u[0] = f2bf(v0.x * s); u[1] = f2bf(v0.y * s); u[2] = f2bf(v0.z * s); u[3] = f2bf(v0.w * s);
      u[4] = f2bf(v1.x * s); u[5] = f2bf(v1.y * s); u[6] = f2bf(v1.z * s); u[7] = f2bf(v1.w * s);
      *reinterpret_cast<u16x8*>(xb + (size_t)n * 128 + chunk * 8) = u;
    }
  }
}

// ---------------- fused gather1 + double GEMM ----------------
// Block owns 16 nodes. Phase A: gather agg tile (16x128 bf16) exactly like gather_kernel<0>,
// but into LDS (XOR-swizzled octs) instead of global. Phase B: MFMA double-GEMM on the tile
// (W1t/W2t read direct from global; 128KB, permanently L2-resident), numerics identical to
// the old gemm12 (same frag scheme, same oct order). Writes s2b (NOT aliasing xb).
__global__ __launch_bounds__(256) void gather_gemm_kernel(
    const bf16_t* __restrict__ feat,   // xb
    const int* __restrict__ row_ptr, const int* __restrict__ csr,
    const bf16_t* __restrict__ W1t,    // [256 n][128 k]
    const bf16_t* __restrict__ W2t,    // [128 n][256 k]
    const float* __restrict__ b1,
    const float* __restrict__ in_norm,
    const float* __restrict__ out_norm,
    bf16_t* __restrict__ s2b) {
  __shared__ __align__(16) bf16_t T[16 * 128];   // 4KB agg tile (swizzled); reused for output
  __shared__ __align__(16) bf16_t H[16 * 256];   // 8KB hidden tile (swizzled)

  // bijective XCD swizzle (neutral-to-slightly-positive; kept from R3)
  int nbk = gridDim.x;
  int q = nbk >> 3, r8 = nbk & 7;
  int xc = blockIdx.x & 7, ob = blockIdx.x >> 3;
  int vb = (xc < r8 ? xc * (q + 1) : r8 * (q + 1) + (xc - r8) * q) + ob;
  int node0 = vb * 16;
  int g = threadIdx.x >> 4;   // node_local 0..15
  int lane = threadIdx.x & 15;
  int node = node0 + g;

  // ---- phase A: gather (identical body to gather_kernel) ----
  int start = row_ptr[node];
  int end = row_ptr[node + 1];
  float a[8];
#pragma unroll
  for (int t = 0; t < 8; t++) a[t] = 0.f;
  int j = start;
  for (; j + 7 < end; j += 8) {
    int4 sa = *reinterpret_cast<const int4*>(csr + j);
    int4 sb = *reinterpret_cast<const int4*>(csr + j + 4);
    u16x8 u0 = *reinterpret_cast<const u16x8*>(feat + (size_t)sa.x * 128 + lane * 8);
    u16x8 u1 = *reinterpret_cast<const u16x8*>(feat + (size_t)sa.y * 128 + lane * 8);
    u16x8 u2 = *reinterpret_cast<const u16x8*>(feat + (size_t)sa.z * 128 + lane * 8);
    u16x8 u3 = *reinterpret_cast<const u16x8*>(feat + (size_t)sa.w * 128 + lane * 8);
    u16x8 u4 = *reinterpret_cast<const u16x8*>(feat + (size_t)sb.x * 128 + lane * 8);
    u16x8 u5 = *reinterpret_cast<const u16x8*>(feat + (size_t)sb.y * 128 + lane * 8);
    u16x8 u6 = *reinterpret_cast<const u16x8*>(feat + (size_t)sb.z * 128 + lane * 8);
    u16x8 u7 = *reinterpret_cast<const u16x8*>(feat + (size_t)sb.w * 128 + lane * 8);
#pragma unroll
    for (int t = 0; t < 8; t++)
      a[t] += ((bf2f((unsigned short)u0[t]) + bf2f((unsigned short)u1[t])) +
               (bf2f((unsigned short)u2[t]) + bf2f((unsigned short)u3[t]))) +
              ((bf2f((unsigned short)u4[t]) + bf2f((unsigned short)u5[t])) +
               (bf2f((unsigned short)u6[t]) + bf2f((unsigned short)u7[t])));
  }
  if (j + 3 < end) {
    int4 sa = *reinterpret_cast<const int4*>(csr + j);
    u16x8 u0 = *reinterpret_cast<const u16x8*>(feat + (size_t)sa.x * 128 + lane * 8);
    u16x8 u1 = *reinterpret_cast<const u16x8*>(feat + (size_t)sa.y * 128 + lane * 8);
    u16x8 u2 = *reinterpret_cast<const u16x8*>(feat + (size_t)sa.z * 128 + lane * 8);
    u16x8 u3 = *reinterpret_cast<const u16x8*>(feat + (size_t)sa.w * 128 + lane * 8);
#pragma unroll
    for (int t = 0; t < 8; t++)
      a[t] += (bf2f((unsigned short)u0[t]) + bf2f((unsigned short)u1[t])) +
              (bf2f((unsigned short)u2[t]) + bf2f((unsigned short)u3[t]));
    j += 4;
  }
  for (; j < end; j++) {
    int s0 = csr[j];
    u16x8 u0 = *reinterpret_cast<const u16x8*>(feat + (size_t)s0 * 128 + lane * 8);
#pragma unroll
    for (int t = 0; t < 8; t++) a[t] += bf2f((unsigned short)u0[t]);
  }
  // round to bf16 (same as old agg1 store) and stash in LDS, oct-swizzled
  {
    u16x8 o8;
#pragma unroll
    for (int t = 0; t < 8; t++) o8[t] = f2bf(a[t]);
    *reinterpret_cast<u16x8*>(&T[g * 128 + ((lane ^ (g & 7)) << 3)]) = o8;
  }
  __syncthreads();

  // ---- phase B: double GEMM on the 16-row tile ----
  const int tid = threadIdx.x;
  const int wv = tid >> 6;        // wave 0..3 (splits n-dim)
  const int l63 = tid & 63;
  const int l15 = l63 & 15;
  const int S = l63 >> 4;         // 0..3
  const int row0 = S * 4;         // C-side base row (0..12)

  float inn[4], onr[4];
#pragma unroll
  for (int reg = 0; reg < 4; reg++) {
    inn[reg] = in_norm[node0 + row0 + reg];
    onr[reg] = out_norm[node0 + row0 + reg];
  }

  // stage 1: H[16][256] = relu((T @ W1t^T) * inn + b1); wave wv covers n in [wv*64, wv*64+64)
  f32x4 acc1[4];
#pragma unroll
  for (int fn = 0; fn < 4; fn++) acc1[fn] = (f32x4){0.f, 0.f, 0.f, 0.f};
#pragma unroll
  for (int ks = 0; ks < 4; ks++) {             // k-steps of 32 (k = 128)
    int oct = ks * 4 + S;
    bf16x8 af = *reinterpret_cast<const bf16x8*>(&T[l15 * 128 + ((oct ^ (l15 & 7)) << 3)]);
#pragma unroll
    for (int fn = 0; fn < 4; fn++) {
      int n = wv * 64 + fn * 16 + l15;
      bf16x8 bf = *reinterpret_cast<const bf16x8*>(W1t + (size_t)n * 128 + oct * 8);
      acc1[fn] = __builtin_amdgcn_mfma_f32_16x16x32_bf16(af, bf, acc1[fn], 0, 0, 0);
    }
  }
#pragma unroll
  for (int fn = 0; fn < 4; fn++) {
    int col = wv * 64 + fn * 16 + l15;
    float bb = b1[col];
#pragma unroll
    for (int reg = 0; reg < 4; reg++) {
      int lr = row0 + reg;
      float v = fmaxf(fmaf(acc1[fn][reg], inn[reg], bb), 0.f);
      int slot = (col >> 3) ^ (lr & 7);
      H[lr * 256 + slot * 8 + (col & 7)] = f2bf(v);
    }
  }
  __syncthreads();

  // stage 2: O[16][128] = (H @ W2t^T) * onr; wave wv covers n in [wv*32, wv*32+32)
  f32x4 acc2[2];
#pragma unroll
  for (int fn = 0; fn < 2; fn++) acc2[fn] = (f32x4){0.f, 0.f, 0.f, 0.f};
#pragma unroll
  for (int ks = 0; ks < 8; ks++) {             // k-steps of 32 (k = 256)
    int oct = ks * 4 + S;
    bf16x8 af = *reinterpret_cast<const bf16x8*>(&H[l15 * 256 + ((oct ^ (l15 & 7)) << 3)]);
#pragma unroll
    for (int fn = 0; fn < 2; fn++) {
      int n = wv * 32 + fn * 16 + l15;
      bf16x8 bf = *reinterpret_cast<const bf16x8*>(W2t + (size_t)n * 256 + oct * 8);
      acc2[fn] = __builtin_amdgcn_mfma_f32_16x16x32_bf16(af, bf, acc2[fn], 0, 0, 0);
    }
  }
  __syncthreads();  // T free for reuse as output staging
#pragma unroll
  for (int fn = 0; fn < 2; fn++) {
    int col = wv * 32 + fn * 16 + l15;
#pragma unroll
    for (int reg = 0; reg < 4; reg++) {
      int lr = row0 + reg;
      T[lr * 128 + col] = f2bf(acc2[fn][reg] * onr[reg]);
    }
  }
  __syncthreads();
  {
    int rr = tid >> 4, cc = (tid & 15) * 8;
    *reinterpret_cast<u16x8*>(s2b + (size_t)(node0 + rr) * 128 + cc) =
        *reinterpret_cast<const u16x8*>(&T[rr * 128 + cc]);
  }
}

// ---------------- gather2 via dense CSR: 16 lanes/node, 16 nodes/block, 8-deep MLP ----------------
// out(f32) = relu(sum * rs[node] + bias[col])
__global__ __launch_bounds__(256) void gather_kernel(
    const bf16_t* __restrict__ feat, const int* __restrict__ row_ptr,
    const int* __restrict__ csr, const float* __restrict__ rs,
    const float* __restrict__ bias, float* __restrict__ outp) {
  // bijective XCD swizzle (grid = 6250, q = 781, r = 2)
  int nbk = gridDim.x;
  int q = nbk >> 3, r = nbk & 7;
  int x = blockIdx.x & 7, o = blockIdx.x >> 3;
  int vb = (x < r ? x * (q + 1) : r * (q + 1) + (x - r) * q) + o;
  int node = vb * 16 + (threadIdx.x >> 4);
  int lane = threadIdx.x & 15;
  int start = row_ptr[node];
  int end = row_ptr[node + 1];
  float a[8];
#pragma unroll
  for (int t = 0; t < 8; t++) a[t] = 0.f;
  int j = start;
  for (; j + 7 < end; j += 8) {
    int4 sa = *reinterpret_cast<const int4*>(csr + j);
    int4 sb = *reinterpret_cast<const int4*>(csr + j + 4);
    u16x8 u0 = *reinterpret_cast<const u16x8*>(feat + (size_t)sa.x * 128 + lane * 8);
    u16x8 u1 = *reinterpret_cast<const u16x8*>(feat + (size_t)sa.y * 128 + lane * 8);
    u16x8 u2 = *reinterpret_cast<const u16x8*>(feat + (size_t)sa.z * 128 + lane * 8);
    u16x8 u3 = *reinterpret_cast<const u16x8*>(feat + (size_t)sa.w * 128 + lane * 8);
    u16x8 u4 = *reinterpret_cast<const u16x8*>(feat + (size_t)sb.x * 128 + lane * 8);
    u16x8 u5 = *reinterpret_cast<const u16x8*>(feat + (size_t)sb.y * 128 + lane * 8);
    u16x8 u6 = *reinterpret_cast<const u16x8*>(feat + (size_t)sb.z * 128 + lane * 8);
    u16x8 u7 = *reinterpret_cast<const u16x8*>(feat + (size_t)sb.w * 128 + lane * 8);
#pragma unroll
    for (int t = 0; t < 8; t++)
      a[t] += ((bf2f((unsigned short)u0[t]) + bf2f((unsigned short)u1[t])) +
               (bf2f((unsigned short)u2[t]) + bf2f((unsigned short)u3[t]))) +
              ((bf2f((unsigned short)u4[t]) + bf2f((unsigned short)u5[t])) +
               (bf2f((unsigned short)u6[t]) + bf2f((unsigned short)u7[t])));
  }
  if (j + 3 < end) {
    int4 sa = *reinterpret_cast<const int4*>(csr + j);
    u16x8 u0 = *reinterpret_cast<const u16x8*>(feat + (size_t)sa.x * 128 + lane * 8);
    u16x8 u1 = *reinterpret_cast<const u16x8*>(feat + (size_t)sa.y * 128 + lane * 8);
    u16x8 u2 = *reinterpret_cast<const u16x8*>(feat + (size_t)sa.z * 128 + lane * 8);
    u16x8 u3 = *reinterpret_cast<const u16x8*>(feat + (size_t)sa.w * 128 + lane * 8);
#pragma unroll
    for (int t = 0; t < 8; t++)
      a[t] += (bf2f((unsigned short)u0[t]) + bf2f((unsigned short)u1[t])) +
              (bf2f((unsigned short)u2[t]) + bf2f((unsigned short)u3[t]));
    j += 4;
  }
  for (; j < end; j++) {
    int s0 = csr[j];
    u16x8 u0 = *reinterpret_cast<const u16x8*>(feat + (size_t)s0 * 128 + lane * 8);
#pragma unroll
    for (int t = 0; t < 8; t++) a[t] += bf2f((unsigned short)u0[t]);
  }
  float s = rs[node];
  const float* bp = bias + lane * 8;
  float4 o0, o1;
  o0.x = fmaxf(fmaf(a[0], s, bp[0]), 0.f);
  o0.y = fmaxf(fmaf(a[1], s, bp[1]), 0.f);
  o0.z = fmaxf(fmaf(a[2], s, bp[2]), 0.f);
  o0.w = fmaxf(fmaf(a[3], s, bp[3]), 0.f);
  o1.x = fmaxf(fmaf(a[4], s, bp[4]), 0.f);
  o1.y = fmaxf(fmaf(a[5], s, bp[5]), 0.f);
  o1.z = fmaxf(fmaf(a[6], s, bp[6]), 0.f);
  o1.w = fmaxf(fmaf(a[7], s, bp[7]), 0.f);
  float* op = outp + (size_t)node * 128 + lane * 8;
  *reinterpret_cast<float4*>(op) = o0;
  *reinterpret_cast<float4*>(op + 4) = o1;
}

extern "C" void kernel_launch(void* const* d_in, const int* in_sizes, int n_in,
                              void* d_out, int out_size, void* d_ws, size_t ws_size,
                              hipStream_t stream) {
  const float* x  = (const float*)d_in[0];
  const float* W1 = (const float*)d_in[1];
  const float* b1 = (const float*)d_in[2];
  const float* W2 = (const float*)d_in[3];
  const float* b2 = (const float*)d_in[4];
  const int* src  = (const int*)d_in[5];
  const int* dst  = (const int*)d_in[6];
  float* out = (float*)d_out;

  char* ws = (char*)d_ws;
  int*           cntD     = (int*)          (ws + 0);          // 391*391*4 = 611,524
  int*           cntS     = (int*)          (ws + 700000);     // 611,524
  int*           binTot   = (int*)          (ws + 1400000);    // 782*4
  int*           binbaseD = (int*)          (ws + 1404000);    // 392*4
  int*           binbaseS = (int*)          (ws + 1406000);    // 392*4
  int*           row_ptr  = (int*)          (ws + 1408000);    // 400,004
  float*         out_norm = (float*)        (ws + 1810000);    // 400,000
  float*         in_norm  = (float*)        (ws + 2210000);    // 400,000
  bf16_t*        W1t      = (bf16_t*)       (ws + 2610000);    // 65,536
  bf16_t*        W2t      = (bf16_t*)       (ws + 2675536);    // 65,536
  unsigned int*  recD     = (unsigned int*) (ws + 2741072);    // 6,400,000
  unsigned char* recS     = (unsigned char*)(ws + 9141072);    // 1,600,000
  int*           csr      = (int*)          (ws + 10741072);   // 6,400,000
  bf16_t*        xb       = (bf16_t*)       (ws + 17141072);   // 25,600,000
  bf16_t*        s2b      = (bf16_t*)       (ws + 42741072);   // 25,600,000 (distinct from xb!)

  // atomic-free CSR build (src-partition-sorted rows)
  hist2_kernel<<<NB, 256, 0, stream>>>(src, dst, cntD, cntS);
  scan_bin_kernel<<<2 * NBIN, 512, 0, stream>>>(cntD, cntS, binTot);
  base_wcast_kernel<<<129, 512, 0, stream>>>(binTot, binbaseD, binbaseS, row_ptr, W1, W2, W1t, W2t);
  scatter_recs_kernel<<<NB, 256, 0, stream>>>(src, dst, cntD, cntS, binbaseD, binbaseS, recD, recS);
  finish2_kernel<<<2 * NBIN, 512, 0, stream>>>(recD, binbaseD, recS, binbaseS,
                                               row_ptr, in_norm, csr, out_norm, x, xb);

  // fused: s2b = ((relu((sum xb[src] @ W1)*in_norm+b1))@W2)*out_norm
  gather_gemm_kernel<<<NNODES / 16, 256, 0, stream>>>(xb, row_ptr, csr, W1t, W2t,
                                                      b1, in_norm, out_norm, s2b);

  // layer 2 aggregate + fused epilogue: out = relu(sum s2b[src] * in_norm + b2)
  gather_kernel<<<NNODES / 16, 256, 0, stream>>>(s2b, row_ptr, csr, in_norm, b2, out);
}

// Round 5
// 281.209 us; speedup vs baseline: 1.0179x; 1.0179x over previous
//
#include <hip/hip_runtime.h>
#include <stdint.h>

#define NNODES 100000
#define NEDGES 1600000
#define NBIN 391        // ceil(NNODES/256), bin = node >> 8
#define EPB 4096        // edges per block in build passes
#define NB 391          // ceil(NEDGES/EPB)

typedef unsigned short bf16_t;
typedef __attribute__((ext_vector_type(8))) short bf16x8;   // MFMA A/B frag (8 bf16)
typedef __attribute__((ext_vector_type(8))) unsigned short u16x8;
typedef __attribute__((ext_vector_type(4))) float f32x4;    // MFMA C/D frag
typedef __attribute__((ext_vector_type(4))) int i32x4;

__device__ __forceinline__ float bf2f(unsigned short u) {
  return __uint_as_float(((unsigned)u) << 16);
}
__device__ __forceinline__ unsigned short f2bf(float f) {
  unsigned u = __float_as_uint(f);
  return (unsigned short)((u + 0x7FFFu + ((u >> 16) & 1u)) >> 16);  // RNE
}
__device__ __forceinline__ void gload_lds16(const void* g, void* lds) {
  __builtin_amdgcn_global_load_lds(
      (const __attribute__((address_space(1))) unsigned int*)g,
      (__attribute__((address_space(3))) unsigned int*)lds, 16, 0, 0);
}

// ---------------- pass 1: global bin totals (LDS hist -> global atomics) ----------------
__global__ __launch_bounds__(256) void histg_kernel(
    const int* __restrict__ src, const int* __restrict__ dst,
    int* __restrict__ binTot) {   // [0..NBIN) = dst side, [NBIN..2*NBIN) = src side
  __shared__ int hD[NBIN], hS[NBIN];
  int blk = blockIdx.x, t = threadIdx.x;
  for (int i = t; i < NBIN; i += 256) { hD[i] = 0; hS[i] = 0; }
  __syncthreads();
  int e0 = blk * EPB + t * 16;
  if (e0 + 15 < NEDGES) {
#pragma unroll
    for (int q = 0; q < 4; q++) {
      int4 s4 = *reinterpret_cast<const int4*>(src + e0 + q * 4);
      int4 d4 = *reinterpret_cast<const int4*>(dst + e0 + q * 4);
      atomicAdd(&hD[d4.x >> 8], 1); atomicAdd(&hS[s4.x >> 8], 1);
      atomicAdd(&hD[d4.y >> 8], 1); atomicAdd(&hS[s4.y >> 8], 1);
      atomicAdd(&hD[d4.z >> 8], 1); atomicAdd(&hS[s4.z >> 8], 1);
      atomicAdd(&hD[d4.w >> 8], 1); atomicAdd(&hS[s4.w >> 8], 1);
    }
  } else {
    for (int e = e0; e < NEDGES && e < e0 + 16; e++) {
      atomicAdd(&hD[dst[e] >> 8], 1);
      atomicAdd(&hS[src[e] >> 8], 1);
    }
  }
  __syncthreads();
  for (int i = t; i < NBIN; i += 256) {
    if (hD[i]) atomicAdd(&binTot[i], hD[i]);
    if (hS[i]) atomicAdd(&binTot[NBIN + i], hS[i]);
  }
}

// ---------------- pass 2 (block 0): bin bases + cursors; blocks 1..: weight cast+transpose ----------------
__global__ __launch_bounds__(512) void base_wcast_kernel(
    const int* __restrict__ binTot, int* __restrict__ binbaseD,
    int* __restrict__ binbaseS, int* __restrict__ cursD, int* __restrict__ cursS,
    int* __restrict__ row_ptr,
    const float* __restrict__ W1, const float* __restrict__ W2,
    bf16_t* __restrict__ W1t, bf16_t* __restrict__ W2t) {
  if (blockIdx.x == 0) {
    __shared__ int lds[512];
    int t = threadIdx.x;
    int v = (t < NBIN) ? binTot[t] : 0;
    lds[t] = v;
    __syncthreads();
    for (int off = 1; off < 512; off <<= 1) {
      int a = (t >= off) ? lds[t - off] : 0;
      __syncthreads();
      lds[t] += a;
      __syncthreads();
    }
    if (t < NBIN) { int b = lds[t] - v; binbaseD[t] = b; cursD[t] = b; }
    if (t == NBIN - 1) { binbaseD[NBIN] = lds[t]; row_ptr[NNODES] = lds[t]; }
    __syncthreads();
    int v2 = (t < NBIN) ? binTot[NBIN + t] : 0;
    lds[t] = v2;
    __syncthreads();
    for (int off = 1; off < 512; off <<= 1) {
      int a = (t >= off) ? lds[t - off] : 0;
      __syncthreads();
      lds[t] += a;
      __syncthreads();
    }
    if (t < NBIN) { int b = lds[t] - v2; binbaseS[t] = b; cursS[t] = b; }
    if (t == NBIN - 1) binbaseS[NBIN] = lds[t];
  } else {
    int i = (blockIdx.x - 1) * 512 + threadIdx.x;  // 0..65535
    if (i < 32768) {
      int n = i / 128, k = i % 128;                 // W1t[n][k] = W1[k][n]
      W1t[i] = f2bf(W1[(size_t)k * 256 + n]);
    } else if (i < 65536) {
      int j = i - 32768;
      int n = j / 256, k = j % 256;                 // W2t[n][k] = W2[k][n]
      W2t[j] = f2bf(W2[(size_t)k * 128 + n]);
    }
  }
}

// ---------------- pass 3: scatter records (in-kernel hist -> range reservation -> scatter) ----------------
__global__ __launch_bounds__(256) void scatter2_kernel(
    const int* __restrict__ src, const int* __restrict__ dst,
    int* __restrict__ cursD, int* __restrict__ cursS,
    unsigned int* __restrict__ recD, unsigned char* __restrict__ recS) {
  __shared__ int hD[NBIN], hS[NBIN];   // hist, then block-local cursors
  int blk = blockIdx.x, t = threadIdx.x;
  for (int i = t; i < NBIN; i += 256) { hD[i] = 0; hS[i] = 0; }
  __syncthreads();
  int e0 = blk * EPB + t * 16;
  if (e0 + 15 < NEDGES) {
#pragma unroll
    for (int q = 0; q < 4; q++) {
      int4 s4 = *reinterpret_cast<const int4*>(src + e0 + q * 4);
      int4 d4 = *reinterpret_cast<const int4*>(dst + e0 + q * 4);
      atomicAdd(&hD[d4.x >> 8], 1); atomicAdd(&hS[s4.x >> 8], 1);
      atomicAdd(&hD[d4.y >> 8], 1); atomicAdd(&hS[s4.y >> 8], 1);
      atomicAdd(&hD[d4.z >> 8], 1); atomicAdd(&hS[s4.z >> 8], 1);
      atomicAdd(&hD[d4.w >> 8], 1); atomicAdd(&hS[s4.w >> 8], 1);
    }
  } else {
    for (int e = e0; e < NEDGES && e < e0 + 16; e++) {
      atomicAdd(&hD[dst[e] >> 8], 1);
      atomicAdd(&hS[src[e] >> 8], 1);
    }
  }
  __syncthreads();
  // reserve a contiguous range per non-empty bin; hD/hS become write cursors
  for (int i = t; i < NBIN; i += 256) {
    int c = hD[i];
    hD[i] = c ? atomicAdd(&cursD[i], c) : 0;
    int c2 = hS[i];
    hS[i] = c2 ? atomicAdd(&cursS[i], c2) : 0;
  }
  __syncthreads();
  if (e0 + 15 < NEDGES) {
#pragma unroll
    for (int q = 0; q < 4; q++) {
      int4 s4 = *reinterpret_cast<const int4*>(src + e0 + q * 4);
      int4 d4 = *reinterpret_cast<const int4*>(dst + e0 + q * 4);
      int ss[4] = {s4.x, s4.y, s4.z, s4.w};
      int dd[4] = {d4.x, d4.y, d4.z, d4.w};
#pragma unroll
      for (int i = 0; i < 4; i++) {
        int s = ss[i], d = dd[i];
        int pos = atomicAdd(&hD[d >> 8], 1);
        recD[pos] = ((unsigned)s << 8) | (unsigned)(d & 255);
        int ps = atomicAdd(&hS[s >> 8], 1);
        recS[ps] = (unsigned char)(s & 255);
      }
    }
  } else {
    for (int e = e0; e < NEDGES && e < e0 + 16; e++) {
      int s = src[e], d = dst[e];
      int pos = atomicAdd(&hD[d >> 8], 1);
      recD[pos] = ((unsigned)s << 8) | (unsigned)(d & 255);
      int ps = atomicAdd(&hS[s >> 8], 1);
      recS[ps] = (unsigned char)(s & 255);
    }
  }
}

// ---------------- fused finish ----------------
// b < NBIN: dst side — in-bin counting sort keyed (residue<<4 | src>>13); row_ptr + in_norm.
// b >= NBIN: src side — outdeg hist -> out_norm, fused cvt x -> xb.
__global__ __launch_bounds__(512) void finish2_kernel(
    const unsigned int* __restrict__ recD, const int* __restrict__ binbaseD,
    const unsigned char* __restrict__ recS, const int* __restrict__ binbaseS,
    int* __restrict__ row_ptr, float* __restrict__ in_norm, int* __restrict__ csr,
    float* __restrict__ out_norm, const float* __restrict__ x, bf16_t* __restrict__ xb) {
  __shared__ int hist[4096];
  __shared__ int cur[4096];
  __shared__ int sc[512];
  __shared__ float onv[256];
  int t = threadIdx.x;
  if (blockIdx.x < NBIN) {
    int b = blockIdx.x;
    int base = binbaseD[b];
    int cnt = binbaseD[b + 1] - base;
    for (int i = t; i < 4096; i += 512) hist[i] = 0;
    __syncthreads();
    const unsigned int* rec = recD + base;
    for (int i = t; i < cnt; i += 512) {
      unsigned int r = rec[i];
      atomicAdd(&hist[((r & 255u) << 4) | (r >> 21)], 1);  // src>>13 = r>>21 (0..12)
    }
    __syncthreads();
    int loc[8];
    int lsum = 0;
#pragma unroll
    for (int i = 0; i < 8; i++) { loc[i] = lsum; lsum += hist[t * 8 + i]; }
    sc[t] = lsum;
    __syncthreads();
    for (int off = 1; off < 512; off <<= 1) {
      int a = (t >= off) ? sc[t - off] : 0;
      __syncthreads();
      sc[t] += a;
      __syncthreads();
    }
    int toff = sc[t] - lsum;  // exclusive across threads
#pragma unroll
    for (int i = 0; i < 8; i++) cur[t * 8 + i] = base + toff + loc[i];
    __syncthreads();
    if (t < 256) {
      int n = (b << 8) + t;
      if (n < NNODES) {
        row_ptr[n] = cur[t * 16];
        int v = 0;
#pragma unroll
        for (int p = 0; p < 16; p++) v += hist[t * 16 + p];
        in_norm[n] = rsqrtf((float)(v > 0 ? v : 1));
      }
    }
    __syncthreads();
    for (int i = t; i < cnt; i += 512) {
      unsigned int r = rec[i];
      int key = ((r & 255u) << 4) | (r >> 21);
      int slot = atomicAdd(&cur[key], 1);
      csr[slot] = (int)(r >> 8);
    }
  } else {
    int b = blockIdx.x - NBIN;
    int base = binbaseS[b];
    int cnt = binbaseS[b + 1] - base;
    if (t < 256) hist[t] = 0;
    __syncthreads();
    const unsigned char* rec = recS + base;
    for (int i = t; i < cnt; i += 512) atomicAdd(&hist[rec[i]], 1);
    __syncthreads();
    int n0 = b << 8;
    if (t < 256) {
      int v = hist[t];
      float on = rsqrtf((float)(v > 0 ? v : 1));
      onv[t] = on;
      int n = n0 + t;
      if (n < NNODES) out_norm[n] = on;
    }
    __syncthreads();
    for (int idx = t; idx < 256 * 16; idx += 512) {
      int r16 = idx >> 4, chunk = idx & 15;
      int n = n0 + r16;
      if (n >= NNODES) break;
      float s = onv[r16];
      const float4* xp = reinterpret_cast<const float4*>(x + (size_t)n * 128 + chunk * 8);
      float4 v0 = xp[0], v1 = xp[1];
      u16x8 u;
      u[0] = f2bf(v0.x * s); u[1] = f2bf(v0.y * s); u[2] = f2bf(v0.z * s); u[3] = f2bf(v0.w * s);
      u[4] = f2bf(v1.x * s); u[5] = f2bf(v1.y * s); u[6] = f2bf(v1.z * s); u[7] = f2bf(v1.w * s);
      *reinterpret_cast<u16x8*>(xb + (size_t)n * 128 + chunk * 8) = u;
    }
  }
}

// ---------------- gather via dense CSR: 16 lanes/node, 16 nodes/block, 8-deep MLP ----------------
// csr index stream + output stream are single-use -> non-temporal, so they don't evict
// the feat table (the only reused data) from L2.
// FIN=0: out(bf16) = sum feat[src]   FIN=1: out(f32) = relu(sum * rs[node] + bias[col])
template <int FIN>
__global__ __launch_bounds__(256) void gather_kernel(
    const bf16_t* __restrict__ feat, const int* __restrict__ row_ptr,
    const int* __restrict__ csr, const float* __restrict__ rs,
    const float* __restrict__ bias, void* __restrict__ outp) {
  // bijective XCD swizzle (grid = 6250, q = 781, r = 2)
  int nbk = gridDim.x;
  int q = nbk >> 3, r = nbk & 7;
  int x = blockIdx.x & 7, o = blockIdx.x >> 3;
  int vb = (x < r ? x * (q + 1) : r * (q + 1) + (x - r) * q) + o;
  int node = vb * 16 + (threadIdx.x >> 4);
  int lane = threadIdx.x & 15;
  int start = row_ptr[node];
  int end = row_ptr[node + 1];
  float a[8];
#pragma unroll
  for (int t = 0; t < 8; t++) a[t] = 0.f;
  int j = start;
  for (; j + 7 < end; j += 8) {
    i32x4 sa = __builtin_nontemporal_load(reinterpret_cast<const i32x4*>(csr + j));
    i32x4 sb = __builtin_nontemporal_load(reinterpret_cast<const i32x4*>(csr + j + 4));
    u16x8 u0 = *reinterpret_cast<const u16x8*>(feat + (size_t)sa[0] * 128 + lane * 8);
    u16x8 u1 = *reinterpret_cast<const u16x8*>(feat + (size_t)sa[1] * 128 + lane * 8);
    u16x8 u2 = *reinterpret_cast<const u16x8*>(feat + (size_t)sa[2] * 128 + lane * 8);
    u16x8 u3 = *reinterpret_cast<const u16x8*>(feat + (size_t)sa[3] * 128 + lane * 8);
    u16x8 u4 = *reinterpret_cast<const u16x8*>(feat + (size_t)sb[0] * 128 + lane * 8);
    u16x8 u5 = *reinterpret_cast<const u16x8*>(feat + (size_t)sb[1] * 128 + lane * 8);
    u16x8 u6 = *reinterpret_cast<const u16x8*>(feat + (size_t)sb[2] * 128 + lane * 8);
    u16x8 u7 = *reinterpret_cast<const u16x8*>(feat + (size_t)sb[3] * 128 + lane * 8);
#pragma unroll
    for (int t = 0; t < 8; t++)
      a[t] += ((bf2f((unsigned short)u0[t]) + bf2f((unsigned short)u1[t])) +
               (bf2f((unsigned short)u2[t]) + bf2f((unsigned short)u3[t]))) +
              ((bf2f((unsigned short)u4[t]) + bf2f((unsigned short)u5[t])) +
               (bf2f((unsigned short)u6[t]) + bf2f((unsigned short)u7[t])));
  }
  if (j + 3 < end) {
    i32x4 sa = __builtin_nontemporal_load(reinterpret_cast<const i32x4*>(csr + j));
    u16x8 u0 = *reinterpret_cast<const u16x8*>(feat + (size_t)sa[0] * 128 + lane * 8);
    u16x8 u1 = *reinterpret_cast<const u16x8*>(feat + (size_t)sa[1] * 128 + lane * 8);
    u16x8 u2 = *reinterpret_cast<const u16x8*>(feat + (size_t)sa[2] * 128 + lane * 8);
    u16x8 u3 = *reinterpret_cast<const u16x8*>(feat + (size_t)sa[3] * 128 + lane * 8);
#pragma unroll
    for (int t = 0; t < 8; t++)
      a[t] += (bf2f((unsigned short)u0[t]) + bf2f((unsigned short)u1[t])) +
              (bf2f((unsigned short)u2[t]) + bf2f((unsigned short)u3[t]));
    j += 4;
  }
  for (; j < end; j++) {
    int s0 = csr[j];
    u16x8 u0 = *reinterpret_cast<const u16x8*>(feat + (size_t)s0 * 128 + lane * 8);
#pragma unroll
    for (int t = 0; t < 8; t++) a[t] += bf2f((unsigned short)u0[t]);
  }
  if (FIN == 0) {
    u16x8 o8;
#pragma unroll
    for (int t = 0; t < 8; t++) o8[t] = f2bf(a[t]);
    __builtin_nontemporal_store(
        o8, reinterpret_cast<u16x8*>((bf16_t*)outp + (size_t)node * 128 + lane * 8));
  } else {
    float s = rs[node];
    const float* bp = bias + lane * 8;
    f32x4 o0, o1;
    o0[0] = fmaxf(fmaf(a[0], s, bp[0]), 0.f);
    o0[1] = fmaxf(fmaf(a[1], s, bp[1]), 0.f);
    o0[2] = fmaxf(fmaf(a[2], s, bp[2]), 0.f);
    o0[3] = fmaxf(fmaf(a[3], s, bp[3]), 0.f);
    o1[0] = fmaxf(fmaf(a[4], s, bp[4]), 0.f);
    o1[1] = fmaxf(fmaf(a[5], s, bp[5]), 0.f);
    o1[2] = fmaxf(fmaf(a[6], s, bp[6]), 0.f);
    o1[3] = fmaxf(fmaf(a[7], s, bp[7]), 0.f);
    float* op = (float*)outp + (size_t)node * 128 + lane * 8;
    __builtin_nontemporal_store(o0, reinterpret_cast<f32x4*>(op));
    __builtin_nontemporal_store(o1, reinterpret_cast<f32x4*>(op + 4));
  }
}

// ---------------- fused double GEMM: s2b = ((relu((agg1@W1)*innorm+b1))@W2)*outnorm ----------------
__global__ __launch_bounds__(256) void gemm12_kernel(
    const bf16_t* __restrict__ A,      // agg1 [NNODES][128]
    const bf16_t* __restrict__ W1t,    // [256 n][128 k]
    const bf16_t* __restrict__ W2t,    // [128 n][256 k]
    const float* __restrict__ b1,
    const float* __restrict__ in_norm,
    const float* __restrict__ out_norm,
    bf16_t* __restrict__ s2b) {        // [NNODES][128]
  __shared__ __align__(16) bf16_t As[64 * 128];    // 16KB (reused as output tile)
  __shared__ __align__(16) bf16_t Wb[128 * 128];   // 32KB
  __shared__ __align__(16) bf16_t H[64 * 256];     // 32KB

  const int tid = threadIdx.x;
  const int lane = tid & 63;
  const int w = tid >> 6;          // wave 0..3
  const int m0 = blockIdx.x * 64;
  const int l15 = lane & 15;
  const int S = lane >> 4;         // 0..3
  const int r = w * 16 + l15;      // A-side row for frags (0..63)
  const int lr0 = w * 16 + S * 4;  // C-side base row

#pragma unroll
  for (int p = 0; p < 4; p++) {
    int pos = p * 256 + tid;
    int rr = pos >> 4, slot = pos & 15;
    int row = m0 + rr; if (row > NNODES - 1) row = NNODES - 1;
    int ko = (slot ^ (rr & 7)) << 3;
    gload_lds16(A + (size_t)row * 128 + ko, &As[(p * 256 + w * 64) * 8]);
  }
#pragma unroll
  for (int p = 0; p < 8; p++) {
    int pos = p * 256 + tid;
    int n = pos >> 4, slot = pos & 15;
    int ko = (slot ^ (n & 7)) << 3;
    gload_lds16(W1t + (size_t)n * 128 + ko, &Wb[(p * 256 + w * 64) * 8]);
  }
  __syncthreads();

  float inn[4];
#pragma unroll
  for (int reg = 0; reg < 4; reg++) {
    int grow = m0 + lr0 + reg;
    inn[reg] = (grow < NNODES) ? in_norm[grow] : 1.0f;
  }

  // ---- stage 1: H = relu((As@W1)*innorm + b1), two n-halves ----
#pragma unroll
  for (int h = 0; h < 2; h++) {
    if (h == 1) {
      __syncthreads();
#pragma unroll
      for (int p = 0; p < 8; p++) {
        int pos = p * 256 + tid;
        int n = pos >> 4, slot = pos & 15;
        int ko = (slot ^ (n & 7)) << 3;
        gload_lds16(W1t + (size_t)(128 + n) * 128 + ko, &Wb[(p * 256 + w * 64) * 8]);
      }
      __syncthreads();
    }
    f32x4 acc1[8];
#pragma unroll
    for (int fn = 0; fn < 8; fn++) acc1[fn] = (f32x4){0.f, 0.f, 0.f, 0.f};
#pragma unroll
    for (int kk8 = 0; kk8 < 16; kk8 += 4) {
      bf16x8 af = *reinterpret_cast<const bf16x8*>(&As[r * 128 + (((kk8 + S) ^ (r & 7)) << 3)]);
#pragma unroll
      for (int fn = 0; fn < 8; fn++) {
        int n = fn * 16 + l15;
        bf16x8 bf = *reinterpret_cast<const bf16x8*>(&Wb[n * 128 + (((kk8 + S) ^ (n & 7)) << 3)]);
        acc1[fn] = __builtin_amdgcn_mfma_f32_16x16x32_bf16(af, bf, acc1[fn], 0, 0, 0);
      }
    }
#pragma unroll
    for (int fn = 0; fn < 8; fn++) {
      int col = h * 128 + fn * 16 + l15;
      float bb = b1[col];
#pragma unroll
      for (int reg = 0; reg < 4; reg++) {
        int lr = lr0 + reg;
        float v = fmaxf(fmaf(acc1[fn][reg], inn[reg], bb), 0.f);
        int slot = (col >> 3) ^ (lr & 7);
        H[lr * 256 + slot * 8 + (col & 7)] = f2bf(v);
      }
    }
  }
  __syncthreads();

  // ---- stage 2: acc2 = H @ W2t, two k-halves ----
  f32x4 acc2[8];
#pragma unroll
  for (int fn = 0; fn < 8; fn++) acc2[fn] = (f32x4){0.f, 0.f, 0.f, 0.f};
#pragma unroll
  for (int kh = 0; kh < 2; kh++) {
#pragma unroll
    for (int p = 0; p < 8; p++) {
      int pos = p * 256 + tid;
      int n = pos >> 4, slot = pos & 15;
      int ko = kh * 128 + ((slot ^ (n & 7)) << 3);
      gload_lds16(W2t + (size_t)n * 256 + ko, &Wb[(p * 256 + w * 64) * 8]);
    }
    __syncthreads();
#pragma unroll
    for (int kk8 = 0; kk8 < 16; kk8 += 4) {
      int oct = kh * 16 + kk8 + S;
      bf16x8 af = *reinterpret_cast<const bf16x8*>(&H[r * 256 + ((oct ^ (r & 7)) << 3)]);
#pragma unroll
      for (int fn = 0; fn < 8; fn++) {
        int n = fn * 16 + l15;
        bf16x8 bf = *reinterpret_cast<const bf16x8*>(&Wb[n * 128 + (((kk8 + S) ^ (n & 7)) << 3)]);
        acc2[fn] = __builtin_amdgcn_mfma_f32_16x16x32_bf16(af, bf, acc2[fn], 0, 0, 0);
      }
    }
    __syncthreads();
  }

  // ---- epilogue: stage output tile in LDS (reuse As), then coalesced 16B stores ----
  float onr[4];
#pragma unroll
  for (int reg = 0; reg < 4; reg++) {
    int grow = m0 + lr0 + reg;
    onr[reg] = (grow < NNODES) ? out_norm[grow] : 0.0f;
  }
#pragma unroll
  for (int fn = 0; fn < 8; fn++) {
    int col = fn * 16 + l15;
#pragma unroll
    for (int reg = 0; reg < 4; reg++) {
      int lr = lr0 + reg;
      As[lr * 128 + col] = f2bf(acc2[fn][reg] * onr[reg]);
    }
  }
  __syncthreads();
#pragma unroll
  for (int p = 0; p < 4; p++) {
    int pos = p * 256 + tid;
    int rr = pos >> 4;
    int cc = (pos & 15) * 8;
    int grow = m0 + rr;
    if (grow < NNODES)
      *reinterpret_cast<u16x8*>(s2b + (size_t)grow * 128 + cc) =
          *reinterpret_cast<const u16x8*>(&As[rr * 128 + cc]);
  }
}

extern "C" void kernel_launch(void* const* d_in, const int* in_sizes, int n_in,
                              void* d_out, int out_size, void* d_ws, size_t ws_size,
                              hipStream_t stream) {
  const float* x  = (const float*)d_in[0];
  const float* W1 = (const float*)d_in[1];
  const float* b1 = (const float*)d_in[2];
  const float* W2 = (const float*)d_in[3];
  const float* b2 = (const float*)d_in[4];
  const int* src  = (const int*)d_in[5];
  const int* dst  = (const int*)d_in[6];
  float* out = (float*)d_out;

  char* ws = (char*)d_ws;
  int*           binTot   = (int*)          (ws + 0);          // 782*4 = 3128
  int*           binbaseD = (int*)          (ws + 4000);       // 392*4
  int*           binbaseS = (int*)          (ws + 6000);       // 392*4
  int*           cursD    = (int*)          (ws + 8000);       // 391*4
  int*           cursS    = (int*)          (ws + 10000);      // 391*4
  int*           row_ptr  = (int*)          (ws + 12000);      // 400,004 -> 412,004
  float*         out_norm = (float*)        (ws + 420000);     // 400,000
  float*         in_norm  = (float*)        (ws + 830000);     // 400,000
  bf16_t*        W1t      = (bf16_t*)       (ws + 1240000);    // 65,536
  bf16_t*        W2t      = (bf16_t*)       (ws + 1305536);    // 65,536
  unsigned int*  recD     = (unsigned int*) (ws + 1371072);    // 6,400,000
  unsigned char* recS     = (unsigned char*)(ws + 7771072);    // 1,600,000
  int*           csr      = (int*)          (ws + 9371072);    // 6,400,000
  bf16_t*        xb       = (bf16_t*)       (ws + 15771072);   // 25,600,000
  bf16_t*        agg1     = (bf16_t*)       (ws + 41371072);   // 25,600,000 -> ends 67.0MB
  bf16_t*        s2b      = xb;                                // reuse after gather1

  hipMemsetAsync(binTot, 0, 2 * NBIN * sizeof(int), stream);

  // atomic-free-ordered CSR build (bin ranges reserved atomically; finish2 sorts in-bin)
  histg_kernel<<<NB, 256, 0, stream>>>(src, dst, binTot);
  base_wcast_kernel<<<129, 512, 0, stream>>>(binTot, binbaseD, binbaseS, cursD, cursS,
                                             row_ptr, W1, W2, W1t, W2t);
  scatter2_kernel<<<NB, 256, 0, stream>>>(src, dst, cursD, cursS, recD, recS);
  finish2_kernel<<<2 * NBIN, 512, 0, stream>>>(recD, binbaseD, recS, binbaseS,
                                               row_ptr, in_norm, csr, out_norm, x, xb);

  // layer 1 aggregate: agg1(bf16)[n] = sum xb[src]
  gather_kernel<0><<<NNODES / 16, 256, 0, stream>>>(xb, row_ptr, csr, nullptr, nullptr, agg1);

  // fused: s2b = ((relu((agg1@W1)*in_norm+b1))@W2)*out_norm
  gemm12_kernel<<<(NNODES + 63) / 64, 256, 0, stream>>>(agg1, W1t, W2t, b1, in_norm, out_norm, s2b);

  // layer 2 aggregate + fused epilogue: out = relu(sum s2b[src] * in_norm + b2)
  gather_kernel<1><<<NNODES / 16, 256, 0, stream>>>(s2b, row_ptr, csr, in_norm, b2, out);
}

// Round 6
// 255.095 us; speedup vs baseline: 1.1221x; 1.1024x over previous
//
#include <hip/hip_runtime.h>
#include <stdint.h>

#define NNODES 100000
#define NEDGES 1600000
#define NBIN 391        // ceil(NNODES/256), bin = node >> 8
#define EPB 4096        // edges per block in build passes
#define NB 391          // ceil(NEDGES/EPB)

typedef unsigned short bf16_t;
typedef __attribute__((ext_vector_type(8))) short bf16x8;   // MFMA A/B frag (8 bf16)
typedef __attribute__((ext_vector_type(8))) unsigned short u16x8;
typedef __attribute__((ext_vector_type(4))) float f32x4;    // MFMA C/D frag

__device__ __forceinline__ float bf2f(unsigned short u) {
  return __uint_as_float(((unsigned)u) << 16);
}
__device__ __forceinline__ unsigned short f2bf(float f) {
  unsigned u = __float_as_uint(f);
  return (unsigned short)((u + 0x7FFFu + ((u >> 16) & 1u)) >> 16);  // RNE
}
__device__ __forceinline__ void gload_lds16(const void* g, void* lds) {
  __builtin_amdgcn_global_load_lds(
      (const __attribute__((address_space(1))) unsigned int*)g,
      (__attribute__((address_space(3))) unsigned int*)lds, 16, 0, 0);
}

// ---------------- pass 1: per-block LDS histograms over dst-bins and src-bins ----------------
// cnt layout: [block][bin] (coalesced write here, coalesced read in scatter)
__global__ __launch_bounds__(256) void hist2_kernel(
    const int* __restrict__ src, const int* __restrict__ dst,
    int* __restrict__ cntD, int* __restrict__ cntS) {
  __shared__ int hD[NBIN], hS[NBIN];
  int blk = blockIdx.x, t = threadIdx.x;
  for (int i = t; i < NBIN; i += 256) { hD[i] = 0; hS[i] = 0; }
  __syncthreads();
  int e0 = blk * EPB + t * 16;
  if (e0 + 15 < NEDGES) {
#pragma unroll
    for (int q = 0; q < 4; q++) {
      int4 s4 = *reinterpret_cast<const int4*>(src + e0 + q * 4);
      int4 d4 = *reinterpret_cast<const int4*>(dst + e0 + q * 4);
      atomicAdd(&hD[d4.x >> 8], 1); atomicAdd(&hS[s4.x >> 8], 1);
      atomicAdd(&hD[d4.y >> 8], 1); atomicAdd(&hS[s4.y >> 8], 1);
      atomicAdd(&hD[d4.z >> 8], 1); atomicAdd(&hS[s4.z >> 8], 1);
      atomicAdd(&hD[d4.w >> 8], 1); atomicAdd(&hS[s4.w >> 8], 1);
    }
  } else {
    for (int e = e0; e < NEDGES && e < e0 + 16; e++) {
      atomicAdd(&hD[dst[e] >> 8], 1);
      atomicAdd(&hS[src[e] >> 8], 1);
    }
  }
  __syncthreads();
  for (int i = t; i < NBIN; i += 256) {
    cntD[(size_t)blk * NBIN + i] = hD[i];
    cntS[(size_t)blk * NBIN + i] = hS[i];
  }
}

// ---------------- pass 2a: per-bin exclusive scan across blocks (in place) ----------------
__global__ __launch_bounds__(512) void scan_bin_kernel(
    int* __restrict__ cntD, int* __restrict__ cntS, int* __restrict__ binTot) {
  __shared__ int lds[512];
  int g = blockIdx.x, t = threadIdx.x;
  int* cnt = (g < NBIN) ? cntD : cntS;
  int gg = (g < NBIN) ? g : g - NBIN;
  int v = (t < NB) ? cnt[(size_t)t * NBIN + gg] : 0;
  lds[t] = v;
  __syncthreads();
  for (int off = 1; off < 512; off <<= 1) {
    int a = (t >= off) ? lds[t - off] : 0;
    __syncthreads();
    lds[t] += a;
    __syncthreads();
  }
  if (t < NB) cnt[(size_t)t * NBIN + gg] = lds[t] - v;  // exclusive
  if (t == 0) binTot[g] = lds[511];
}

// ---------------- pass 2b (block 0): bin bases; blocks 1..: weight cast+transpose ----------------
__global__ __launch_bounds__(512) void base_wcast_kernel(
    const int* __restrict__ binTot, int* __restrict__ binbaseD,
    int* __restrict__ binbaseS, int* __restrict__ row_ptr,
    const float* __restrict__ W1, const float* __restrict__ W2,
    bf16_t* __restrict__ W1t, bf16_t* __restrict__ W2t) {
  if (blockIdx.x == 0) {
    __shared__ int lds[512];
    int t = threadIdx.x;
    int v = (t < NBIN) ? binTot[t] : 0;
    lds[t] = v;
    __syncthreads();
    for (int off = 1; off < 512; off <<= 1) {
      int a = (t >= off) ? lds[t - off] : 0;
      __syncthreads();
      lds[t] += a;
      __syncthreads();
    }
    if (t < NBIN) binbaseD[t] = lds[t] - v;
    if (t == NBIN - 1) { binbaseD[NBIN] = lds[t]; row_ptr[NNODES] = lds[t]; }
    __syncthreads();
    int v2 = (t < NBIN) ? binTot[NBIN + t] : 0;
    lds[t] = v2;
    __syncthreads();
    for (int off = 1; off < 512; off <<= 1) {
      int a = (t >= off) ? lds[t - off] : 0;
      __syncthreads();
      lds[t] += a;
      __syncthreads();
    }
    if (t < NBIN) binbaseS[t] = lds[t] - v2;
    if (t == NBIN - 1) binbaseS[NBIN] = lds[t];
  } else {
    int i = (blockIdx.x - 1) * 512 + threadIdx.x;  // 0..65535
    if (i < 32768) {
      int n = i / 128, k = i % 128;                 // W1t[n][k] = W1[k][n]
      W1t[i] = f2bf(W1[(size_t)k * 256 + n]);
    } else if (i < 65536) {
      int j = i - 32768;
      int n = j / 256, k = j % 256;                 // W2t[n][k] = W2[k][n]
      W2t[j] = f2bf(W2[(size_t)k * 128 + n]);
    }
  }
}

// ---------------- pass 3: scatter records to bins (LDS cursors, no global atomics) ----------------
__global__ __launch_bounds__(256) void scatter_recs_kernel(
    const int* __restrict__ src, const int* __restrict__ dst,
    const int* __restrict__ cntD, const int* __restrict__ cntS,
    const int* __restrict__ binbaseD, const int* __restrict__ binbaseS,
    unsigned int* __restrict__ recD, unsigned char* __restrict__ recS) {
  __shared__ int cD[NBIN], cS[NBIN];
  int blk = blockIdx.x, t = threadIdx.x;
  for (int i = t; i < NBIN; i += 256) {
    cD[i] = binbaseD[i] + cntD[(size_t)blk * NBIN + i];
    cS[i] = binbaseS[i] + cntS[(size_t)blk * NBIN + i];
  }
  __syncthreads();
  int e0 = blk * EPB + t * 16;
  if (e0 + 15 < NEDGES) {
#pragma unroll
    for (int q = 0; q < 4; q++) {
      int4 s4 = *reinterpret_cast<const int4*>(src + e0 + q * 4);
      int4 d4 = *reinterpret_cast<const int4*>(dst + e0 + q * 4);
      int ss[4] = {s4.x, s4.y, s4.z, s4.w};
      int dd[4] = {d4.x, d4.y, d4.z, d4.w};
#pragma unroll
      for (int i = 0; i < 4; i++) {
        int s = ss[i], d = dd[i];
        int pos = atomicAdd(&cD[d >> 8], 1);
        recD[pos] = ((unsigned)s << 8) | (unsigned)(d & 255);
        int ps = atomicAdd(&cS[s >> 8], 1);
        recS[ps] = (unsigned char)(s & 255);
      }
    }
  } else {
    for (int e = e0; e < NEDGES && e < e0 + 16; e++) {
      int s = src[e], d = dst[e];
      int pos = atomicAdd(&cD[d >> 8], 1);
      recD[pos] = ((unsigned)s << 8) | (unsigned)(d & 255);
      int ps = atomicAdd(&cS[s >> 8], 1);
      recS[ps] = (unsigned char)(s & 255);
    }
  }
}

// ---------------- fused finish ----------------
// b < NBIN: dst side — in-bin counting sort keyed (residue<<4 | src>>13) so each CSR
//           row's src list is grouped by ascending 8K-node partition (L2 sweep locality);
//           also emits row_ptr + in_norm.
// b >= NBIN: src side — outdeg hist -> out_norm, fused cvt x -> xb.
__global__ __launch_bounds__(512) void finish2_kernel(
    const unsigned int* __restrict__ recD, const int* __restrict__ binbaseD,
    const unsigned char* __restrict__ recS, const int* __restrict__ binbaseS,
    int* __restrict__ row_ptr, float* __restrict__ in_norm, int* __restrict__ csr,
    float* __restrict__ out_norm, const float* __restrict__ x, bf16_t* __restrict__ xb) {
  __shared__ int hist[4096];
  __shared__ int cur[4096];
  __shared__ int sc[512];
  __shared__ float onv[256];
  int t = threadIdx.x;
  if (blockIdx.x < NBIN) {
    int b = blockIdx.x;
    int base = binbaseD[b];
    int cnt = binbaseD[b + 1] - base;
    for (int i = t; i < 4096; i += 512) hist[i] = 0;
    __syncthreads();
    const unsigned int* rec = recD + base;
    for (int i = t; i < cnt; i += 512) {
      unsigned int r = rec[i];
      atomicAdd(&hist[((r & 255u) << 4) | (r >> 21)], 1);  // src>>13 = r>>21 (0..12)
    }
    __syncthreads();
    int loc[8];
    int lsum = 0;
#pragma unroll
    for (int i = 0; i < 8; i++) { loc[i] = lsum; lsum += hist[t * 8 + i]; }
    sc[t] = lsum;
    __syncthreads();
    for (int off = 1; off < 512; off <<= 1) {
      int a = (t >= off) ? sc[t - off] : 0;
      __syncthreads();
      sc[t] += a;
      __syncthreads();
    }
    int toff = sc[t] - lsum;  // exclusive across threads
#pragma unroll
    for (int i = 0; i < 8; i++) cur[t * 8 + i] = base + toff + loc[i];
    __syncthreads();
    if (t < 256) {
      int n = (b << 8) + t;
      if (n < NNODES) {
        row_ptr[n] = cur[t * 16];
        int v = 0;
#pragma unroll
        for (int p = 0; p < 16; p++) v += hist[t * 16 + p];
        in_norm[n] = rsqrtf((float)(v > 0 ? v : 1));
      }
    }
    __syncthreads();
    for (int i = t; i < cnt; i += 512) {
      unsigned int r = rec[i];
      int key = ((r & 255u) << 4) | (r >> 21);
      int slot = atomicAdd(&cur[key], 1);
      csr[slot] = (int)(r >> 8);
    }
  } else {
    int b = blockIdx.x - NBIN;
    int base = binbaseS[b];
    int cnt = binbaseS[b + 1] - base;
    if (t < 256) hist[t] = 0;
    __syncthreads();
    const unsigned char* rec = recS + base;
    for (int i = t; i < cnt; i += 512) atomicAdd(&hist[rec[i]], 1);
    __syncthreads();
    int n0 = b << 8;
    if (t < 256) {
      int v = hist[t];
      float on = rsqrtf((float)(v > 0 ? v : 1));
      onv[t] = on;
      int n = n0 + t;
      if (n < NNODES) out_norm[n] = on;
    }
    __syncthreads();
    for (int idx = t; idx < 256 * 16; idx += 512) {
      int r16 = idx >> 4, chunk = idx & 15;
      int n = n0 + r16;
      if (n >= NNODES) break;
      float s = onv[r16];
      const float4* xp = reinterpret_cast<const float4*>(x + (size_t)n * 128 + chunk * 8);
      float4 v0 = xp[0], v1 = xp[1];
      u16x8 u;
      u[0] = f2bf(v0.x * s); u[1] = f2bf(v0.y * s); u[2] = f2bf(v0.z * s); u[3] = f2bf(v0.w * s);
      u[4] = f2bf(v1.x * s); u[5] = f2bf(v1.y * s); u[6] = f2bf(v1.z * s); u[7] = f2bf(v1.w * s);
      *reinterpret_cast<u16x8*>(xb + (size_t)n * 128 + chunk * 8) = u;
    }
  }
}

// ---------------- gather via dense CSR: 16 lanes/node, 16 nodes/block, 8-deep MLP ----------------
// Block->node mapping is XCD-contiguous (bijective m204 swizzle): HW dispatches blockIdx
// round-robin over 8 XCDs; remap so each XCD owns a contiguous ~12.5K-node range.
// FIN=0: out(bf16) = sum feat[src]   FIN=1: out(f32) = relu(sum * rs[node] + bias[col])
template <int FIN>
__global__ __launch_bounds__(256) void gather_kernel(
    const bf16_t* __restrict__ feat, const int* __restrict__ row_ptr,
    const int* __restrict__ csr, const float* __restrict__ rs,
    const float* __restrict__ bias, void* __restrict__ outp) {
  // bijective XCD swizzle (grid = 6250, q = 781, r = 2)
  int nbk = gridDim.x;
  int q = nbk >> 3, r = nbk & 7;
  int x = blockIdx.x & 7, o = blockIdx.x >> 3;
  int vb = (x < r ? x * (q + 1) : r * (q + 1) + (x - r) * q) + o;
  int node = vb * 16 + (threadIdx.x >> 4);
  int lane = threadIdx.x & 15;
  int start = row_ptr[node];
  int end = row_ptr[node + 1];
  float a[8];
#pragma unroll
  for (int t = 0; t < 8; t++) a[t] = 0.f;
  int j = start;
  for (; j + 7 < end; j += 8) {
    int4 sa = *reinterpret_cast<const int4*>(csr + j);
    int4 sb = *reinterpret_cast<const int4*>(csr + j + 4);
    u16x8 u0 = *reinterpret_cast<const u16x8*>(feat + (size_t)sa.x * 128 + lane * 8);
    u16x8 u1 = *reinterpret_cast<const u16x8*>(feat + (size_t)sa.y * 128 + lane * 8);
    u16x8 u2 = *reinterpret_cast<const u16x8*>(feat + (size_t)sa.z * 128 + lane * 8);
    u16x8 u3 = *reinterpret_cast<const u16x8*>(feat + (size_t)sa.w * 128 + lane * 8);
    u16x8 u4 = *reinterpret_cast<const u16x8*>(feat + (size_t)sb.x * 128 + lane * 8);
    u16x8 u5 = *reinterpret_cast<const u16x8*>(feat + (size_t)sb.y * 128 + lane * 8);
    u16x8 u6 = *reinterpret_cast<const u16x8*>(feat + (size_t)sb.z * 128 + lane * 8);
    u16x8 u7 = *reinterpret_cast<const u16x8*>(feat + (size_t)sb.w * 128 + lane * 8);
#pragma unroll
    for (int t = 0; t < 8; t++)
      a[t] += ((bf2f((unsigned short)u0[t]) + bf2f((unsigned short)u1[t])) +
               (bf2f((unsigned short)u2[t]) + bf2f((unsigned short)u3[t]))) +
              ((bf2f((unsigned short)u4[t]) + bf2f((unsigned short)u5[t])) +
               (bf2f((unsigned short)u6[t]) + bf2f((unsigned short)u7[t])));
  }
  if (j + 3 < end) {
    int4 sa = *reinterpret_cast<const int4*>(csr + j);
    u16x8 u0 = *reinterpret_cast<const u16x8*>(feat + (size_t)sa.x * 128 + lane * 8);
    u16x8 u1 = *reinterpret_cast<const u16x8*>(feat + (size_t)sa.y * 128 + lane * 8);
    u16x8 u2 = *reinterpret_cast<const u16x8*>(feat + (size_t)sa.z * 128 + lane * 8);
    u16x8 u3 = *reinterpret_cast<const u16x8*>(feat + (size_t)sa.w * 128 + lane * 8);
#pragma unroll
    for (int t = 0; t < 8; t++)
      a[t] += (bf2f((unsigned short)u0[t]) + bf2f((unsigned short)u1[t])) +
              (bf2f((unsigned short)u2[t]) + bf2f((unsigned short)u3[t]));
    j += 4;
  }
  for (; j < end; j++) {
    int s0 = csr[j];
    u16x8 u0 = *reinterpret_cast<const u16x8*>(feat + (size_t)s0 * 128 + lane * 8);
#pragma unroll
    for (int t = 0; t < 8; t++) a[t] += bf2f((unsigned short)u0[t]);
  }
  if (FIN == 0) {
    u16x8 o8;
#pragma unroll
    for (int t = 0; t < 8; t++) o8[t] = f2bf(a[t]);
    *reinterpret_cast<u16x8*>((bf16_t*)outp + (size_t)node * 128 + lane * 8) = o8;
  } else {
    float s = rs[node];
    const float* bp = bias + lane * 8;
    float4 o0, o1;
    o0.x = fmaxf(fmaf(a[0], s, bp[0]), 0.f);
    o0.y = fmaxf(fmaf(a[1], s, bp[1]), 0.f);
    o0.z = fmaxf(fmaf(a[2], s, bp[2]), 0.f);
    o0.w = fmaxf(fmaf(a[3], s, bp[3]), 0.f);
    o1.x = fmaxf(fmaf(a[4], s, bp[4]), 0.f);
    o1.y = fmaxf(fmaf(a[5], s, bp[5]), 0.f);
    o1.z = fmaxf(fmaf(a[6], s, bp[6]), 0.f);
    o1.w = fmaxf(fmaf(a[7], s, bp[7]), 0.f);
    float* op = (float*)outp + (size_t)node * 128 + lane * 8;
    *reinterpret_cast<float4*>(op) = o0;
    *reinterpret_cast<float4*>(op + 4) = o1;
  }
}

// ---------------- fused double GEMM: s2b = ((relu((agg1@W1)*innorm+b1))@W2)*outnorm ----------------
__global__ __launch_bounds__(256) void gemm12_kernel(
    const bf16_t* __restrict__ A,      // agg1 [NNODES][128]
    const bf16_t* __restrict__ W1t,    // [256 n][128 k]
    const bf16_t* __restrict__ W2t,    // [128 n][256 k]
    const float* __restrict__ b1,
    const float* __restrict__ in_norm,
    const float* __restrict__ out_norm,
    bf16_t* __restrict__ s2b) {        // [NNODES][128]
  __shared__ __align__(16) bf16_t As[64 * 128];    // 16KB (reused as output tile)
  __shared__ __align__(16) bf16_t Wb[128 * 128];   // 32KB
  __shared__ __align__(16) bf16_t H[64 * 256];     // 32KB

  const int tid = threadIdx.x;
  const int lane = tid & 63;
  const int w = tid >> 6;          // wave 0..3
  const int m0 = blockIdx.x * 64;
  const int l15 = lane & 15;
  const int S = lane >> 4;         // 0..3
  const int r = w * 16 + l15;      // A-side row for frags (0..63)
  const int lr0 = w * 16 + S * 4;  // C-side base row

#pragma unroll
  for (int p = 0; p < 4; p++) {
    int pos = p * 256 + tid;
    int rr = pos >> 4, slot = pos & 15;
    int row = m0 + rr; if (row > NNODES - 1) row = NNODES - 1;
    int ko = (slot ^ (rr & 7)) << 3;
    gload_lds16(A + (size_t)row * 128 + ko, &As[(p * 256 + w * 64) * 8]);
  }
#pragma unroll
  for (int p = 0; p < 8; p++) {
    int pos = p * 256 + tid;
    int n = pos >> 4, slot = pos & 15;
    int ko = (slot ^ (n & 7)) << 3;
    gload_lds16(W1t + (size_t)n * 128 + ko, &Wb[(p * 256 + w * 64) * 8]);
  }
  __syncthreads();

  float inn[4];
#pragma unroll
  for (int reg = 0; reg < 4; reg++) {
    int grow = m0 + lr0 + reg;
    inn[reg] = (grow < NNODES) ? in_norm[grow] : 1.0f;
  }

  // ---- stage 1: H = relu((As@W1)*innorm + b1), two n-halves ----
#pragma unroll
  for (int h = 0; h < 2; h++) {
    if (h == 1) {
      __syncthreads();
#pragma unroll
      for (int p = 0; p < 8; p++) {
        int pos = p * 256 + tid;
        int n = pos >> 4, slot = pos & 15;
        int ko = (slot ^ (n & 7)) << 3;
        gload_lds16(W1t + (size_t)(128 + n) * 128 + ko, &Wb[(p * 256 + w * 64) * 8]);
      }
      __syncthreads();
    }
    f32x4 acc1[8];
#pragma unroll
    for (int fn = 0; fn < 8; fn++) acc1[fn] = (f32x4){0.f, 0.f, 0.f, 0.f};
#pragma unroll
    for (int kk8 = 0; kk8 < 16; kk8 += 4) {
      bf16x8 af = *reinterpret_cast<const bf16x8*>(&As[r * 128 + (((kk8 + S) ^ (r & 7)) << 3)]);
#pragma unroll
      for (int fn = 0; fn < 8; fn++) {
        int n = fn * 16 + l15;
        bf16x8 bf = *reinterpret_cast<const bf16x8*>(&Wb[n * 128 + (((kk8 + S) ^ (n & 7)) << 3)]);
        acc1[fn] = __builtin_amdgcn_mfma_f32_16x16x32_bf16(af, bf, acc1[fn], 0, 0, 0);
      }
    }
#pragma unroll
    for (int fn = 0; fn < 8; fn++) {
      int col = h * 128 + fn * 16 + l15;
      float bb = b1[col];
#pragma unroll
      for (int reg = 0; reg < 4; reg++) {
        int lr = lr0 + reg;
        float v = fmaxf(fmaf(acc1[fn][reg], inn[reg], bb), 0.f);
        int slot = (col >> 3) ^ (lr & 7);
        H[lr * 256 + slot * 8 + (col & 7)] = f2bf(v);
      }
    }
  }
  __syncthreads();

  // ---- stage 2: acc2 = H @ W2t, two k-halves ----
  f32x4 acc2[8];
#pragma unroll
  for (int fn = 0; fn < 8; fn++) acc2[fn] = (f32x4){0.f, 0.f, 0.f, 0.f};
#pragma unroll
  for (int kh = 0; kh < 2; kh++) {
#pragma unroll
    for (int p = 0; p < 8; p++) {
      int pos = p * 256 + tid;
      int n = pos >> 4, slot = pos & 15;
      int ko = kh * 128 + ((slot ^ (n & 7)) << 3);
      gload_lds16(W2t + (size_t)n * 256 + ko, &Wb[(p * 256 + w * 64) * 8]);
    }
    __syncthreads();
#pragma unroll
    for (int kk8 = 0; kk8 < 16; kk8 += 4) {
      int oct = kh * 16 + kk8 + S;
      bf16x8 af = *reinterpret_cast<const bf16x8*>(&H[r * 256 + ((oct ^ (r & 7)) << 3)]);
#pragma unroll
      for (int fn = 0; fn < 8; fn++) {
        int n = fn * 16 + l15;
        bf16x8 bf = *reinterpret_cast<const bf16x8*>(&Wb[n * 128 + (((kk8 + S) ^ (n & 7)) << 3)]);
        acc2[fn] = __builtin_amdgcn_mfma_f32_16x16x32_bf16(af, bf, acc2[fn], 0, 0, 0);
      }
    }
    __syncthreads();
  }

  // ---- epilogue: stage output tile in LDS (reuse As), then coalesced 16B stores ----
  float onr[4];
#pragma unroll
  for (int reg = 0; reg < 4; reg++) {
    int grow = m0 + lr0 + reg;
    onr[reg] = (grow < NNODES) ? out_norm[grow] : 0.0f;
  }
#pragma unroll
  for (int fn = 0; fn < 8; fn++) {
    int col = fn * 16 + l15;
#pragma unroll
    for (int reg = 0; reg < 4; reg++) {
      int lr = lr0 + reg;
      As[lr * 128 + col] = f2bf(acc2[fn][reg] * onr[reg]);
    }
  }
  __syncthreads();
#pragma unroll
  for (int p = 0; p < 4; p++) {
    int pos = p * 256 + tid;
    int rr = pos >> 4;
    int cc = (pos & 15) * 8;
    int grow = m0 + rr;
    if (grow < NNODES)
      *reinterpret_cast<u16x8*>(s2b + (size_t)grow * 128 + cc) =
          *reinterpret_cast<const u16x8*>(&As[rr * 128 + cc]);
  }
}

extern "C" void kernel_launch(void* const* d_in, const int* in_sizes, int n_in,
                              void* d_out, int out_size, void* d_ws, size_t ws_size,
                              hipStream_t stream) {
  const float* x  = (const float*)d_in[0];
  const float* W1 = (const float*)d_in[1];
  const float* b1 = (const float*)d_in[2];
  const float* W2 = (const float*)d_in[3];
  const float* b2 = (const float*)d_in[4];
  const int* src  = (const int*)d_in[5];
  const int* dst  = (const int*)d_in[6];
  float* out = (float*)d_out;

  char* ws = (char*)d_ws;
  int*           cntD     = (int*)          (ws + 0);          // 391*391*4 = 611,524
  int*           cntS     = (int*)          (ws + 700000);     // 611,524
  int*           binTot   = (int*)          (ws + 1400000);    // 782*4
  int*           binbaseD = (int*)          (ws + 1404000);    // 392*4
  int*           binbaseS = (int*)          (ws + 1406000);    // 392*4
  int*           row_ptr  = (int*)          (ws + 1408000);    // 400,004
  float*         out_norm = (float*)        (ws + 1810000);    // 400,000
  float*         in_norm  = (float*)        (ws + 2210000);    // 400,000
  bf16_t*        W1t      = (bf16_t*)       (ws + 2610000);    // 65,536
  bf16_t*        W2t      = (bf16_t*)       (ws + 2675536);    // 65,536
  unsigned int*  recD     = (unsigned int*) (ws + 2741072);    // 6,400,000
  unsigned char* recS     = (unsigned char*)(ws + 9141072);    // 1,600,000
  int*           csr      = (int*)          (ws + 10741072);   // 6,400,000
  bf16_t*        xb       = (bf16_t*)       (ws + 17141072);   // 25,600,000
  bf16_t*        agg1     = (bf16_t*)       (ws + 42741072);   // 25,600,000 -> ends 68.3MB
  bf16_t*        s2b      = xb;                                // reuse after gather1

  // atomic-free CSR build (src-partition-sorted rows)
  hist2_kernel<<<NB, 256, 0, stream>>>(src, dst, cntD, cntS);
  scan_bin_kernel<<<2 * NBIN, 512, 0, stream>>>(cntD, cntS, binTot);
  base_wcast_kernel<<<129, 512, 0, stream>>>(binTot, binbaseD, binbaseS, row_ptr, W1, W2, W1t, W2t);
  scatter_recs_kernel<<<NB, 256, 0, stream>>>(src, dst, cntD, cntS, binbaseD, binbaseS, recD, recS);
  finish2_kernel<<<2 * NBIN, 512, 0, stream>>>(recD, binbaseD, recS, binbaseS,
                                               row_ptr, in_norm, csr, out_norm, x, xb);

  // layer 1 aggregate: agg1(bf16)[n] = sum xb[src]
  gather_kernel<0><<<NNODES / 16, 256, 0, stream>>>(xb, row_ptr, csr, nullptr, nullptr, agg1);

  // fused: s2b = ((relu((agg1@W1)*in_norm+b1))@W2)*out_norm
  gemm12_kernel<<<(NNODES + 63) / 64, 256, 0, stream>>>(agg1, W1t, W2t, b1, in_norm, out_norm, s2b);

  // layer 2 aggregate + fused epilogue: out = relu(sum s2b[src] * in_norm + b2)
  gather_kernel<1><<<NNODES / 16, 256, 0, stream>>>(s2b, row_ptr, csr, in_norm, b2, out);
}